// Round 10
// baseline (313.716 us; speedup 1.0000x reference)
//
#include <hip/hip_runtime.h>
#include <hip/hip_bf16.h>

#define B_TOK 8192
#define D_DIM 3072
#define H_DIM 128
#define O_DIM 10
#define N_EXP 8

#define BM 128             // k2 row-block (BM=64 regressed: doubles B-panel restaging)
#define BK2 128            // K-tile (24 iters over D=3072)
#define HLDS_STRIDE 136    // bf16 elems; row byte stride 272
#define ESTRIDE 4096       // static slots per expert (>25 sigma above mean 2048)

typedef __bf16 bf16x8 __attribute__((ext_vector_type(8)));
typedef float  f32x4  __attribute__((ext_vector_type(4)));
typedef unsigned short us8 __attribute__((ext_vector_type(8)));

// fp32 -> bf16 round-to-nearest-even
__device__ __forceinline__ unsigned short f2bf(float f) {
  unsigned int u = __float_as_uint(f);
  unsigned int r = (u + 0x7FFFu + ((u >> 16) & 1u)) >> 16;
  return (unsigned short)r;
}

__device__ __forceinline__ void async16(const void* g, void* l) {
  __builtin_amdgcn_global_load_lds(
      (const __attribute__((address_space(1))) void*)g,
      (__attribute__((address_space(3))) void*)l,
      16, 0, 0);
}

// ---------------- KA: pure cast copy x (fp32) -> xb (bf16) ----------------
// Textbook copy shape (m13 pattern): grid-stride, 2x float4 read + us8 write,
// no LDS, no cross-lane, 32 waves/CU. Decisive probe: if THIS also plateaus
// at ~1.6 TB/s, the k1a plateau was a machine/stream property, not kernel shape.
__global__ __launch_bounds__(256) void ka_cast(const float* __restrict__ x,
                                               unsigned short* __restrict__ xb) {
  const size_t NT = (size_t)B_TOK * D_DIM / 8;  // 3145728 us8-units
  size_t i = (size_t)blockIdx.x * 256 + threadIdx.x;
  for (; i < NT; i += 524288) {                 // 2048 blocks * 256 thr; 6 iters
    const float4* p = (const float4*)(x + i * 8);
    const float4 a = p[0];
    const float4 b = p[1];
    us8 v;
    v[0] = f2bf(a.x); v[1] = f2bf(a.y); v[2] = f2bf(a.z); v[3] = f2bf(a.w);
    v[4] = f2bf(b.x); v[5] = f2bf(b.y); v[6] = f2bf(b.z); v[7] = f2bf(b.w);
    *(us8*)(xb + i * 8) = v;
  }
}

// ---------------- KB: gating g = x@Wg + bg (fp32), top-2, scatter ----------------
// x is L3-hot after KA. 1024 blocks x 8 tokens (1 token/wave-pass, 2 passes).
// Per token: 12 independent hoisted float4 x-loads; Wg rows (d..d+3, 8 experts)
// = 32 contiguous floats = one 128B line per lane (L1-hot, 96KB total).
// Butterfly reduce -> lane0 top-2 (value-tracked, no dynamic indexing) ->
// block-aggregated atomics -> direct tlist/wslot write (k1c absorbed).
__global__ __launch_bounds__(256) void kb_gate(
    const float* __restrict__ x, const float* __restrict__ Wg,
    const float* __restrict__ bg,
    int* __restrict__ cnt, int* __restrict__ tlist, float* __restrict__ wslot) {
  __shared__ int lcnt[N_EXP], gbase[N_EXP];
  __shared__ float bgs[N_EXP];
  __shared__ int ti0[8], ti1[8], tl0[8], tl1[8];
  __shared__ float tw0[8], tw1[8];
  const int tid  = threadIdx.x;
  const int lane = tid & 63;
  const int wv   = tid >> 6;
  if (tid < N_EXP) { lcnt[tid] = 0; bgs[tid] = bg[tid]; }
  __syncthreads();

#pragma unroll
  for (int it = 0; it < 2; ++it) {
    const int slot = wv * 2 + it;
    const int tok  = blockIdx.x * 8 + slot;
    const float* xr = x + (size_t)tok * D_DIM + lane * 4;

    float4 xv[12];
#pragma unroll
    for (int s = 0; s < 12; ++s) xv[s] = *(const float4*)(xr + s * 256);

    float a[N_EXP];
#pragma unroll
    for (int n = 0; n < N_EXP; ++n) a[n] = 0.f;

#pragma unroll
    for (int s = 0; s < 12; ++s) {
      const float4* wp = (const float4*)(Wg + (size_t)(s * 256 + lane * 4) * N_EXP);
#pragma unroll
      for (int j = 0; j < 4; ++j) {
        const float4 wa = wp[2 * j];
        const float4 wb = wp[2 * j + 1];
        const float xe = (j == 0) ? xv[s].x : (j == 1) ? xv[s].y : (j == 2) ? xv[s].z : xv[s].w;
        a[0] = fmaf(xe, wa.x, a[0]);
        a[1] = fmaf(xe, wa.y, a[1]);
        a[2] = fmaf(xe, wa.z, a[2]);
        a[3] = fmaf(xe, wa.w, a[3]);
        a[4] = fmaf(xe, wb.x, a[4]);
        a[5] = fmaf(xe, wb.y, a[5]);
        a[6] = fmaf(xe, wb.z, a[6]);
        a[7] = fmaf(xe, wb.w, a[7]);
      }
    }

#pragma unroll
    for (int n = 0; n < N_EXP; ++n) {
#pragma unroll
      for (int off = 32; off > 0; off >>= 1)
        a[n] += __shfl_xor(a[n], off, 64);
    }

    if (lane == 0) {
      float g[N_EXP];
#pragma unroll
      for (int n = 0; n < N_EXP; ++n) g[n] = a[n] + bgs[n];
      float m0 = g[0]; int i0 = 0;
#pragma unroll
      for (int n = 1; n < N_EXP; ++n)
        if (g[n] > m0) { m0 = g[n]; i0 = n; }
      float m1 = -3.4e38f; int i1 = 0;
#pragma unroll
      for (int n = 0; n < N_EXP; ++n)
        if (n != i0 && g[n] > m1) { m1 = g[n]; i1 = n; }
      const float e1  = expf(m1 - m0);
      const float inv = 1.f / (1.f + e1);
      ti0[slot] = i0; ti1[slot] = i1;
      tw0[slot] = inv; tw1[slot] = e1 * inv;
      tl0[slot] = atomicAdd(&lcnt[i0], 1);
      tl1[slot] = atomicAdd(&lcnt[i1], 1);
    }
  }
  __syncthreads();
  if (tid < N_EXP) gbase[tid] = atomicAdd(&cnt[tid], lcnt[tid]);
  __syncthreads();
  if (tid < 8) {
    const int tok = blockIdx.x * 8 + tid;
    int p0 = gbase[ti0[tid]] + tl0[tid]; p0 = p0 < ESTRIDE ? p0 : ESTRIDE - 1;
    int p1 = gbase[ti1[tid]] + tl1[tid]; p1 = p1 < ESTRIDE ? p1 : ESTRIDE - 1;
    tlist[ti0[tid] * ESTRIDE + p0] = tok;
    tlist[ti1[tid] * ESTRIDE + p1] = tok;
    wslot[ti0[tid] * ESTRIDE + p0] = tw0[tid];
    wslot[ti1[tid] * ESTRIDE + p1] = tw1[tid];
  }
}

// ---------------- K0: W1 [8][3072][128] fp32 -> W1^T [8][128][3072] bf16 ----------------
__global__ __launch_bounds__(256) void k0_w1_transpose(const float* __restrict__ W1,
                                                       unsigned short* __restrict__ w1t) {
  __shared__ __align__(16) unsigned short lds[64 * 72];  // [h][72]
  const int e  = blockIdx.z;
  const int d0 = blockIdx.x * 64;
  const int h0 = blockIdx.y * 64;
  const int tid = threadIdx.x;

  const float* src = W1 + ((size_t)e * D_DIM + d0) * H_DIM + h0;
  const int hl = tid & 63;   // h lane
  const int dg = tid >> 6;   // 0..3
#pragma unroll
  for (int k = 0; k < 16; ++k) {
    const int d = dg + 4 * k;
    lds[hl * 72 + d] = f2bf(src[(size_t)d * H_DIM + hl]);
  }
  __syncthreads();

  unsigned short* dst = w1t + ((size_t)e * H_DIM + h0) * D_DIM + d0;
  const int q  = tid & 7;    // d-oct
  const int h1 = tid >> 3;   // 0..31
#pragma unroll
  for (int k = 0; k < 2; ++k) {
    const int h = h1 + 32 * k;
    const int d = q * 8;
    us8 v = *(const us8*)(lds + h * 72 + d);
    *(us8*)(dst + (size_t)h * D_DIM + d) = v;
  }
}

// ---------------- K2: sparse per-expert h=relu(x@W1+b1); y=h@W2+b2,
//                  weighted atomic combine into out ----------------
// BK=128 dbuf. LDS rows are 256B (bank-degenerate), so blocks are stored with a
// rotate-by-row swizzle: block b of row r lives at position (b + r) mod 16.
// The rotation is applied to each lane's GLOBAL column offset (wave-uniform LDS
// base preserved for global_load_lds); reads apply the inverse -> conflict-free.
// Epilogue weights each row's y by its routing weight and atomically adds into
// out[t] (exactly 2 adds per output element; commutative -> deterministic).
__global__ __launch_bounds__(256) void k2_experts(
    const unsigned short* __restrict__ xb,    // [B][D] bf16
    const unsigned short* __restrict__ w1t,   // [N][H][D] bf16
    const float* __restrict__ b1,             // [N][H]
    const float* __restrict__ W2,             // [N][H][O]
    const float* __restrict__ b2,             // [N][O]
    const int* __restrict__ cnt, const int* __restrict__ tlist,
    const float* __restrict__ wslot,
    float* __restrict__ out) {                // [B][O], pre-zeroed
  const int e    = blockIdx.y;
  int n_e        = cnt[e];
  n_e            = n_e < ESTRIDE ? n_e : ESTRIDE;
  const int row0 = blockIdx.x * BM;
  if (row0 >= n_e) return;

  __shared__ __align__(16) unsigned short sm[65536 + 2048];
  unsigned short* h_lds   = sm;
  unsigned short* w2t_lds = sm + 65536;

  const int tid  = threadIdx.x;
  const int lane = tid & 63;
  const int wv   = tid >> 6;
  const int quad = lane >> 4;
  const int cl   = lane & 15;

  // staging bases: lane (quad, cl) stages row j*4+quad, global block (cl - (j*4+quad)) & 15
  const unsigned short* Abase[8];
  const unsigned short* Bbase[8];
#pragma unroll
  for (int j = 0; j < 8; ++j) {
    const int rloc = wv * 32 + j * 4 + quad;
    int gr = row0 + rloc;
    gr = gr < n_e ? gr : n_e - 1;
    const int koff = ((cl - (j * 4 + quad)) & 15) * 8;
    Abase[j] = xb + (size_t)tlist[e * ESTRIDE + gr] * D_DIM + koff;
    Bbase[j] = w1t + ((size_t)e * H_DIM + rloc) * D_DIM + koff;
  }

#define STAGE(it, pp)                                                     \
  {                                                                       \
    const int ko = (it) * BK2;                                            \
    unsigned short* abuf = sm + (pp) * 32768;                             \
    unsigned short* bbuf = sm + 16384 + (pp) * 32768;                     \
    _Pragma("unroll")                                                     \
    for (int j = 0; j < 8; ++j) {                                         \
      const int ldsrow = (wv * 32 + j * 4) * BK2;                         \
      async16(Abase[j] + ko, abuf + ldsrow);                              \
      async16(Bbase[j] + ko, bbuf + ldsrow);                              \
    }                                                                     \
  }

  STAGE(0, 0);

  // stage W2^T swizzled: element (o, hh) -> o*128 + (((hh>>3)+o)&15)*8 + (hh&7)
  const float* W2e = W2 + (size_t)e * H_DIM * O_DIM;
  for (int idx = tid; idx < 16 * 128; idx += 256) {
    const int o = idx >> 7, hh = idx & 127;
    const float v = (o < O_DIM) ? W2e[hh * O_DIM + o] : 0.f;
    w2t_lds[o * 128 + ((((hh >> 3) + o) & 15) * 8) + (hh & 7)] = f2bf(v);
  }

  const int mhalf = (wv >> 1) * 64;
  const int nhalf = (wv & 1) * 64;

  f32x4 acc[4][4];
#pragma unroll
  for (int i = 0; i < 4; ++i)
#pragma unroll
    for (int j = 0; j < 4; ++j)
      acc[i][j] = (f32x4){0.f, 0.f, 0.f, 0.f};

  const int NIT = D_DIM / BK2;  // 24
  for (int it = 0; it < NIT; ++it) {
    __syncthreads();
    if (it + 1 < NIT) STAGE(it + 1, (it + 1) & 1);
    const unsigned short* al = sm + (it & 1) * 32768;
    const unsigned short* bl = sm + 16384 + (it & 1) * 32768;
#pragma unroll
    for (int kk = 0; kk < 4; ++kk) {
      const int pos = ((kk * 4 + quad + cl) & 15) * 8;  // swizzled k-block
      bf16x8 af[4], bfr[4];
#pragma unroll
      for (int mi = 0; mi < 4; ++mi)
        af[mi] = *(const bf16x8*)(al + (mhalf + mi * 16 + cl) * BK2 + pos);
#pragma unroll
      for (int ni = 0; ni < 4; ++ni)
        bfr[ni] = *(const bf16x8*)(bl + (nhalf + ni * 16 + cl) * BK2 + pos);
#pragma unroll
      for (int mi = 0; mi < 4; ++mi)
#pragma unroll
        for (int ni = 0; ni < 4; ++ni)
          acc[mi][ni] = __builtin_amdgcn_mfma_f32_16x16x32_bf16(af[mi], bfr[ni], acc[mi][ni], 0, 0, 0);
    }
  }
  __syncthreads();

  // epilogue 1: h = relu(acc + b1) -> h_lds (bf16). C/D layout: col=lane&15, row=quad*4+r
  const float* b1e = b1 + e * H_DIM;
#pragma unroll
  for (int ni = 0; ni < 4; ++ni) {
    const int col  = nhalf + ni * 16 + cl;
    const float bias = b1e[col];
#pragma unroll
    for (int mi = 0; mi < 4; ++mi) {
      const int rbase = mhalf + mi * 16 + (quad << 2);
#pragma unroll
      for (int r = 0; r < 4; ++r) {
        float v = acc[mi][ni][r] + bias;
        v = v > 0.f ? v : 0.f;
        h_lds[(rbase + r) * HLDS_STRIDE + col] = f2bf(v);
      }
    }
  }
  __syncthreads();

  // epilogue 2: y[128x16] = h[128x128] @ W2[128x16]; weighted atomic combine
  f32x4 acc2[2];
  acc2[0] = (f32x4){0.f, 0.f, 0.f, 0.f};
  acc2[1] = (f32x4){0.f, 0.f, 0.f, 0.f};
#pragma unroll
  for (int ks = 0; ks < 4; ++ks) {
    const int krd = ks * 32 + quad * 8;
    bf16x8 bfr = *(const bf16x8*)(w2t_lds + cl * 128 + ((ks * 4 + quad + cl) & 15) * 8);
#pragma unroll
    for (int mi = 0; mi < 2; ++mi) {
      bf16x8 afr = *(const bf16x8*)(h_lds + (wv * 32 + mi * 16 + cl) * HLDS_STRIDE + krd);
      acc2[mi] = __builtin_amdgcn_mfma_f32_16x16x32_bf16(afr, bfr, acc2[mi], 0, 0, 0);
    }
  }
  const int o = cl;
  if (o < O_DIM) {
    const float bias2 = b2[e * O_DIM + o];
#pragma unroll
    for (int mi = 0; mi < 2; ++mi) {
#pragma unroll
      for (int r = 0; r < 4; ++r) {
        const int rl = wv * 32 + mi * 16 + (quad << 2) + r;
        const int slot = row0 + rl;
        if (slot < n_e) {
          const int t = tlist[e * ESTRIDE + slot];
          const float w = wslot[e * ESTRIDE + slot];
          atomicAdd(out + (size_t)t * O_DIM + o, w * (acc2[mi][r] + bias2));
        }
      }
    }
  }
}

extern "C" void kernel_launch(void* const* d_in, const int* in_sizes, int n_in,
                              void* d_out, int out_size, void* d_ws, size_t ws_size,
                              hipStream_t stream) {
  const float* x  = (const float*)d_in[0];
  const float* Wg = (const float*)d_in[1];
  const float* bg = (const float*)d_in[2];
  const float* W1 = (const float*)d_in[3];
  const float* b1 = (const float*)d_in[4];
  const float* W2 = (const float*)d_in[5];
  const float* b2 = (const float*)d_in[6];
  float* out = (float*)d_out;

  char* ws = (char*)d_ws;
  unsigned short* xb  = (unsigned short*)ws;                 // 50331648 B
  unsigned short* w1t = (unsigned short*)(ws + 50331648);    // 6291456 B
  int*    cnt   = (int*)   (ws + 56623104);                  // 128 B
  int*    tlist = (int*)   (ws + 56623232);                  // 131072 B (8*4096*4)
  float*  wslot = (float*) (ws + 56754304);                  // 131072 B
                                                             // total ~56.9 MB

  (void)hipMemsetAsync(cnt, 0, N_EXP * sizeof(int), stream);
  (void)hipMemsetAsync(out, 0, (size_t)B_TOK * O_DIM * sizeof(float), stream);
  ka_cast<<<dim3(2048), dim3(256), 0, stream>>>(x, xb);
  kb_gate<<<dim3(B_TOK / 8), dim3(256), 0, stream>>>(x, Wg, bg, cnt, tlist, wslot);
  k0_w1_transpose<<<dim3(48, 2, 8), dim3(256), 0, stream>>>(W1, w1t);
  k2_experts<<<dim3(ESTRIDE / BM, N_EXP), dim3(256), 0, stream>>>(
      xb, w1t, b1, W2, b2, cnt, tlist, wslot, out);
}